// Round 1
// baseline (12981.316 us; speedup 1.0000x reference)
//
#include <hip/hip_runtime.h>

typedef unsigned long long u64;

#define SEG_N     8192
#define NSEG      2
#define M_PER_SEG 2048
#define M_TOTAL   4096
#define CFEAT     64
#define COUT      128
#define NSAMPLE   16
#define DPAIRS    34          // 67 dims padded to 68 (pad dim = 0)

#define FPS_WGS_PER_SEG 16
#define FPS_PTS_PER_WG  512
#define FPS_THREADS     256
#define FPS_LDS_BYTES   (DPAIRS * FPS_PTS_PER_WG * 2 * (int)sizeof(float))  // 139264

// d_out layout (floats): new_xyz | new_feat | new_offset | new_vel
#define OUT_XYZ   0
#define OUT_FEAT  12288      // 4096*3
#define OUT_OFF   536576     // + 4096*128
#define OUT_VEL   536578     // + 2

// d_ws layout (bytes)
#define WS_CAND 0            // u64 cand[2][2][16]  (parity, seg, wg) = 512 B
#define WS_FPS  512          // int fps_idx[2][2048]
#define WS_KNN  16896        // int knn[4096][16]

// ---------------------------------------------------------------------------
// FPS: 16 WGs per segment, each owns 512 points LDS-resident (transposed,
// dim-pair major). Per step: local min-dist update + argmax, publish packed
// candidate with step tag (parity double buffer), poll all 16 slots, identical
// winner reduction everywhere, reload q coords from read-only global X.
// ---------------------------------------------------------------------------
__global__ __launch_bounds__(FPS_THREADS)
void fps_kernel(const float* __restrict__ xyz, const float* __restrict__ feat,
                u64* __restrict__ cand, int* __restrict__ fps_idx)
{
#pragma clang fp contract(off)
  extern __shared__ float ldsx[];  // [DPAIRS][512][2] : ((dp*512)+p)*2 + l
  __shared__ __align__(16) float qbuf[68];
  __shared__ float rwd[4];
  __shared__ int   rwi[4];
  __shared__ u64   winsh;

  const int tid = threadIdx.x;
  const int s   = blockIdx.x >> 4;
  const int wg  = blockIdx.x & 15;
  const int pbase = wg * FPS_PTS_PER_WG;
  const int grow  = s * SEG_N + pbase;

  // stage feat dims 3..66 (global-coalesced reads)
  for (int e = tid; e < FPS_PTS_PER_WG * 64; e += FPS_THREADS) {
    int p = e >> 6, c = e & 63;
    int d = 3 + c;
    ldsx[((d >> 1) * FPS_PTS_PER_WG + p) * 2 + (d & 1)] =
        feat[(size_t)(grow + p) * CFEAT + c];
  }
  // xyz dims 0..2
  for (int e = tid; e < FPS_PTS_PER_WG * 3; e += FPS_THREADS) {
    int p = e / 3, d = e - p * 3;
    ldsx[((d >> 1) * FPS_PTS_PER_WG + p) * 2 + (d & 1)] =
        xyz[(size_t)(grow + p) * 3 + d];
  }
  // pad dim 67 = 0
  for (int p = tid; p < FPS_PTS_PER_WG; p += FPS_THREADS)
    ldsx[(33 * FPS_PTS_PER_WG + p) * 2 + 1] = 0.f;

  // q for step 1 = segment point 0
  if (tid < 68) {
    float v = 0.f;
    if (tid < 3)       v = xyz[(size_t)(s * SEG_N) * 3 + tid];
    else if (tid < 67) v = feat[(size_t)(s * SEG_N) * CFEAT + (tid - 3)];
    qbuf[tid] = v;
  }
  if (tid == 0 && wg == 0) fps_idx[s * M_PER_SEG] = 0;
  __syncthreads();

  float D0 = 1e10f, D1 = 1e10f;
  const float4* xp  = (const float4*)ldsx;  // index: dp*256 + tid
  const float2* q2p = (const float2*)qbuf;

  for (int t = 1; t < M_PER_SEG; ++t) {
    // numpy-style pairwise sum: 8 strided accumulators, no fma contraction
    float r0[8] = {0,0,0,0,0,0,0,0};
    float r1[8] = {0,0,0,0,0,0,0,0};
    #pragma unroll
    for (int dp = 0; dp < DPAIRS; ++dp) {
      float4 v = xp[dp * 256 + tid];   // {p0.d0, p0.d1, p1.d0, p1.d1}
      float2 q = q2p[dp];
      float t00 = v.x - q.x, t01 = v.y - q.y;
      float t10 = v.z - q.x, t11 = v.w - q.y;
      float s00 = t00 * t00, s01 = t01 * t01;
      float s10 = t10 * t10, s11 = t11 * t11;
      r0[(2*dp) & 7]     += s00;
      r0[(2*dp + 1) & 7] += s01;
      r1[(2*dp) & 7]     += s10;
      r1[(2*dp + 1) & 7] += s11;
    }
    float a0 = ((r0[0]+r0[1])+(r0[2]+r0[3])) + ((r0[4]+r0[5])+(r0[6]+r0[7]));
    float a1 = ((r1[0]+r1[1])+(r1[2]+r1[3])) + ((r1[4]+r1[5])+(r1[6]+r1[7]));
    D0 = fminf(D0, a0);
    D1 = fminf(D1, a1);

    // local argmax, ties -> lowest index
    float bd; int bi;
    if (D1 > D0) { bd = D1; bi = pbase + 2*tid + 1; }
    else         { bd = D0; bi = pbase + 2*tid;     }
    #pragma unroll
    for (int off = 32; off >= 1; off >>= 1) {
      float od = __shfl_xor(bd, off);
      int   oi = __shfl_xor(bi, off);
      if (od > bd || (od == bd && oi < bi)) { bd = od; bi = oi; }
    }
    if ((tid & 63) == 0) { rwd[tid >> 6] = bd; rwi[tid >> 6] = bi; }
    __syncthreads();

    if (tid == 0) {
      bd = rwd[0]; bi = rwi[0];
      #pragma unroll
      for (int w2 = 1; w2 < 4; ++w2) {
        float od = rwd[w2]; int oi = rwi[w2];
        if (od > bd || (od == bd && oi < bi)) { bd = od; bi = oi; }
      }
      u64 pack = ((u64)(unsigned)t << 45)
               | ((u64)__float_as_uint(bd) << 13)
               | (u64)(unsigned)(8191 - bi);
      __hip_atomic_store(&cand[(((unsigned)t & 1u) * NSEG + s) * FPS_WGS_PER_SEG + wg],
                         pack, __ATOMIC_RELEASE, __HIP_MEMORY_SCOPE_AGENT);
    }

    // poll all 16 slots of my segment (one 128B line), then max-reduce
    if (tid < FPS_WGS_PER_SEG) {
      const u64* slot = &cand[(((unsigned)t & 1u) * NSEG + s) * FPS_WGS_PER_SEG + tid];
      u64 v;
      for (;;) {
        v = __hip_atomic_load(slot, __ATOMIC_ACQUIRE, __HIP_MEMORY_SCOPE_AGENT);
        if ((unsigned)(v >> 45) == (unsigned)t) break;
        __builtin_amdgcn_s_sleep(1);
      }
      #pragma unroll
      for (int off = 8; off >= 1; off >>= 1) {
        u64 o = __shfl_xor(v, off, 16);
        if (o > v) v = o;
      }
      if (tid == 0) winsh = v;
    }
    __syncthreads();

    int qi = 8191 - (int)(winsh & 0x1FFFu);
    if (tid == 0 && wg == 0) fps_idx[s * M_PER_SEG + t] = qi;

    // reload q coords from read-only global X (L2-cached)
    if (tid < 68) {
      float v = 0.f;
      if (tid < 3)       v = xyz[(size_t)(s * SEG_N + qi) * 3 + tid];
      else if (tid < 67) v = feat[(size_t)(s * SEG_N + qi) * CFEAT + (tid - 3)];
      qbuf[tid] = v;
    }
    __syncthreads();
  }
}

// ---------------------------------------------------------------------------
__global__ __launch_bounds__(256)
void gather_kernel(const float* __restrict__ xyz, const float* __restrict__ vel,
                   const int* __restrict__ fps_idx, float* __restrict__ out)
{
  int i = blockIdx.x * 256 + threadIdx.x;
  if (i >= M_TOTAL) return;
  int s = i >> 11, r = i & 2047;
  int g = s * SEG_N + fps_idx[s * M_PER_SEG + r];
  out[OUT_XYZ + i*3 + 0] = xyz[(size_t)g*3 + 0];
  out[OUT_XYZ + i*3 + 1] = xyz[(size_t)g*3 + 1];
  out[OUT_XYZ + i*3 + 2] = xyz[(size_t)g*3 + 2];
  out[OUT_VEL + i*3 + 0] = vel[(size_t)g*3 + 0];
  out[OUT_VEL + i*3 + 1] = vel[(size_t)g*3 + 1];
  out[OUT_VEL + i*3 + 2] = vel[(size_t)g*3 + 2];
  if (i == 0) { out[OUT_OFF] = 2048.0f; out[OUT_OFF + 1] = 4096.0f; }
}

// ---------------------------------------------------------------------------
// kNN: 16 queries/WG, 16 scanner-threads/query. Phase 1: per-thread sorted
// top-16 (med3 chain, values only) over stride-16 candidates from LDS tiles;
// 16-way merge -> exact global 16th-smallest T. Phase 2: rescan, collect
// d2 <= T*(1+eps), pick 16 by (d2, idx).
// ---------------------------------------------------------------------------
#define KNN_TILE 1024
__global__ __launch_bounds__(256)
void knn_kernel(const float* __restrict__ xyz, const float* __restrict__ out,
                int* __restrict__ knn)
{
  __shared__ float px[KNN_TILE], py[KNN_TILE], pz[KNN_TILE];
  __shared__ float ldK[16][16][16];
  __shared__ float Tq[16];
  __shared__ float dbuf[16][24];
  __shared__ int   cbuf[16][24];
  __shared__ int   cnt[16];

  const int tid = threadIdx.x;
  const int ql = tid >> 4, j = tid & 15;
  const int qg = blockIdx.x * 16 + ql;
  const int s  = qg >> 11;
  const float qx = out[OUT_XYZ + qg*3 + 0];
  const float qy = out[OUT_XYZ + qg*3 + 1];
  const float qz = out[OUT_XYZ + qg*3 + 2];
  const float sq = qx*qx + qy*qy + qz*qz;

  float K[16];
  #pragma unroll
  for (int r = 0; r < 16; ++r) K[r] = 3.4e38f;

  for (int tile = 0; tile < SEG_N / KNN_TILE; ++tile) {
    __syncthreads();
    for (int u = tid; u < KNN_TILE; u += 256) {
      size_t g = (size_t)(s * SEG_N + tile * KNN_TILE + u);
      px[u] = xyz[g*3+0]; py[u] = xyz[g*3+1]; pz[u] = xyz[g*3+2];
    }
    __syncthreads();
    #pragma unroll 4
    for (int i = 0; i < KNN_TILE / 16; ++i) {
      int c = i * 16 + j;                       // conflict-free: 16 banks, bcast x4
      float x = px[c], y = py[c], z = pz[c];
      float sp  = x*x + y*y + z*z;
      float dot = qx*x + qy*y + qz*z;
      float d2  = (sq + sp) - 2.0f * dot;
      #pragma unroll
      for (int r = 15; r >= 1; --r)             // branchless sorted insert
        K[r] = fminf(fmaxf(d2, K[r-1]), K[r]);  // med3(d2, K[r-1], K[r])
      K[0] = fminf(K[0], d2);
    }
  }
  #pragma unroll
  for (int r = 0; r < 16; ++r) ldK[ql][j][r] = K[r];
  __syncthreads();

  {
    int head = 0;
    float T = 3.4e38f;
    for (int r = 0; r < 16; ++r) {
      float val = (head < 16) ? ldK[ql][j][head] : 3.4e38f;
      float mv = val; int ml = j;
      #pragma unroll
      for (int off = 8; off >= 1; off >>= 1) {
        float ov = __shfl_xor(mv, off, 16);
        int   ol = __shfl_xor(ml, off, 16);
        if (ov < mv || (ov == mv && ol < ml)) { mv = ov; ml = ol; }
      }
      if (j == ml) head++;
      T = mv;
    }
    if (j == 0) { Tq[ql] = T; cnt[ql] = 0; }
  }
  __syncthreads();
  const float T  = Tq[ql];
  const float Tm = T + fabsf(T) * 1e-6f + 1e-30f;

  for (int tile = 0; tile < SEG_N / KNN_TILE; ++tile) {
    __syncthreads();
    for (int u = tid; u < KNN_TILE; u += 256) {
      size_t g = (size_t)(s * SEG_N + tile * KNN_TILE + u);
      px[u] = xyz[g*3+0]; py[u] = xyz[g*3+1]; pz[u] = xyz[g*3+2];
    }
    __syncthreads();
    for (int i = 0; i < KNN_TILE / 16; ++i) {
      int c = i * 16 + j;
      float x = px[c], y = py[c], z = pz[c];
      float sp  = x*x + y*y + z*z;
      float dot = qx*x + qy*y + qz*z;
      float d2  = (sq + sp) - 2.0f * dot;
      if (d2 <= Tm) {
        int pos = atomicAdd(&cnt[ql], 1);
        if (pos < 24) { dbuf[ql][pos] = d2; cbuf[ql][pos] = tile * KNN_TILE + c; }
      }
    }
  }
  __syncthreads();

  if (j == 0) {
    int n = cnt[ql]; if (n > 24) n = 24;
    for (int r = 0; r < NSAMPLE; ++r) {
      float bv = 3.4e38f; int bc = 0, bp = -1;
      for (int e = 0; e < n; ++e) {
        float dv = dbuf[ql][e]; int cc = cbuf[ql][e];
        if (dv < bv || (dv == bv && cc < bc)) { bv = dv; bc = cc; bp = e; }
      }
      if (bp >= 0) dbuf[ql][bp] = 3.4e38f;
      knn[qg * NSAMPLE + r] = bc;
    }
  }
}

// ---------------------------------------------------------------------------
// Gather 16 neighbor feature rows, Linear(64->128) no bias, ReLU, max over k.
// One WG (128 threads = output channels) per query; W rows live in VGPRs.
// ---------------------------------------------------------------------------
__global__ __launch_bounds__(128)
void gemm_kernel(const float* __restrict__ feat, const float* __restrict__ W,
                 const int* __restrict__ knn, float* __restrict__ out)
{
  __shared__ __align__(16) float f[NSAMPLE][CFEAT];
  __shared__ int kid[NSAMPLE];
  const int tid = threadIdx.x;
  const int q = blockIdx.x;
  const int s = q >> 11;
  if (tid < NSAMPLE) kid[tid] = knn[q * NSAMPLE + tid];
  __syncthreads();
  for (int e = tid; e < NSAMPLE * CFEAT; e += 128) {
    int k = e >> 6, c = e & 63;
    f[k][c] = feat[(size_t)(s * SEG_N + kid[k]) * CFEAT + c];
  }
  float4 w[16];
  const float4* Wrow = (const float4*)(W + (size_t)tid * CFEAT);
  #pragma unroll
  for (int c4 = 0; c4 < 16; ++c4) w[c4] = Wrow[c4];
  __syncthreads();

  float m = -3.4e38f;
  #pragma unroll
  for (int k = 0; k < NSAMPLE; ++k) {
    float acc = 0.f;
    const float4* frow = (const float4*)&f[k][0];
    #pragma unroll
    for (int c4 = 0; c4 < 16; ++c4) {
      float4 fv = frow[c4];
      acc += fv.x * w[c4].x + fv.y * w[c4].y + fv.z * w[c4].z + fv.w * w[c4].w;
    }
    m = fmaxf(m, acc);
  }
  out[OUT_FEAT + (size_t)q * COUT + tid] = fmaxf(m, 0.f);
}

// ---------------------------------------------------------------------------
extern "C" void kernel_launch(void* const* d_in, const int* in_sizes, int n_in,
                              void* d_out, int out_size, void* d_ws, size_t ws_size,
                              hipStream_t stream)
{
  const float* xyz  = (const float*)d_in[0];
  const float* feat = (const float*)d_in[1];
  // d_in[2] = offset (segment sizes are fixed by the problem)
  const float* vel  = (const float*)d_in[3];
  const float* W    = (const float*)d_in[4];
  float* out = (float*)d_out;
  char*  ws  = (char*)d_ws;
  u64* cand    = (u64*)(ws + WS_CAND);
  int* fps_idx = (int*)(ws + WS_FPS);
  int* knn     = (int*)(ws + WS_KNN);

  // parity-tagged candidate slots must start clean every launch
  hipMemsetAsync(cand, 0, 512, stream);

  (void)hipFuncSetAttribute((const void*)fps_kernel,
                            hipFuncAttributeMaxDynamicSharedMemorySize,
                            FPS_LDS_BYTES);
  fps_kernel<<<NSEG * FPS_WGS_PER_SEG, FPS_THREADS, FPS_LDS_BYTES, stream>>>(
      xyz, feat, cand, fps_idx);
  gather_kernel<<<M_TOTAL / 256, 256, 0, stream>>>(xyz, vel, fps_idx, out);
  knn_kernel<<<M_TOTAL / 16, 256, 0, stream>>>(xyz, out, knn);
  gemm_kernel<<<M_TOTAL, 128, 0, stream>>>(feat, W, knn, out);
}

// Round 2
// 7543.118 us; speedup vs baseline: 1.7209x; 1.7209x over previous
//
#include <hip/hip_runtime.h>

typedef unsigned long long u64;

#define SEG_N     8192
#define NSEG      2
#define M_PER_SEG 2048
#define M_TOTAL   4096
#define CFEAT     64
#define COUT      128
#define NSAMPLE   16
#define DPAIRS    34          // 67 dims padded to 68 (pad dim = 0)

#define FPS_WGS_PER_SEG 16
#define FPS_PTS_PER_WG  512
#define FPS_THREADS     256
#define FPS_SLOTS       64    // 16 WGs x 4 waves, per segment
#define FPS_LDS_BYTES   (DPAIRS * FPS_PTS_PER_WG * 2 * (int)sizeof(float))  // 139264

// d_out layout (floats): new_xyz | new_feat | new_offset | new_vel
#define OUT_XYZ   0
#define OUT_FEAT  12288      // 4096*3
#define OUT_OFF   536576     // + 4096*128
#define OUT_VEL   536578     // + 2

// d_ws layout (bytes)
#define WS_CAND 0            // u64 cand[2][2][64]  (parity, seg, wg*4+wave) = 2048 B
#define WS_FPS  2048         // int fps_idx[2][2048]
#define WS_KNN  18432        // int knn[4096][16]

// ---------------------------------------------------------------------------
// FPS: 16 WGs per segment, each owns 512 points LDS-resident (transposed,
// dim-pair major). Per step: local min-dist update + per-wave argmax; each
// wave's lane 0 publishes a step-tagged packed candidate (RELAXED agent
// atomic -- tag+payload share one 8B word, so no acquire/release cache
// maintenance is needed; parity double-buffering makes reuse safe). Wave 0
// polls all 64 slots (one lane each), butterfly-reduces the winner, reloads
// q's coords from read-only global X (L2-hot), writes qbuf. ONE barrier/step.
// ---------------------------------------------------------------------------
__global__ __launch_bounds__(FPS_THREADS)
void fps_kernel(const float* __restrict__ xyz, const float* __restrict__ feat,
                u64* __restrict__ cand, int* __restrict__ fps_idx)
{
#pragma clang fp contract(off)
  extern __shared__ float ldsx[];  // [DPAIRS][512][2] : ((dp*512)+p)*2 + l
  __shared__ __align__(16) float qbuf[68];

  const int tid  = threadIdx.x;
  const int lane = tid & 63;
  const int wv   = tid >> 6;
  const int s    = blockIdx.x >> 4;
  const int wg   = blockIdx.x & 15;
  const int pbase = wg * FPS_PTS_PER_WG;
  const int grow  = s * SEG_N + pbase;

  // stage feat dims 3..66 (global-coalesced reads)
  for (int e = tid; e < FPS_PTS_PER_WG * 64; e += FPS_THREADS) {
    int p = e >> 6, c = e & 63;
    int d = 3 + c;
    ldsx[((d >> 1) * FPS_PTS_PER_WG + p) * 2 + (d & 1)] =
        feat[(size_t)(grow + p) * CFEAT + c];
  }
  // xyz dims 0..2
  for (int e = tid; e < FPS_PTS_PER_WG * 3; e += FPS_THREADS) {
    int p = e / 3, d = e - p * 3;
    ldsx[((d >> 1) * FPS_PTS_PER_WG + p) * 2 + (d & 1)] =
        xyz[(size_t)(grow + p) * 3 + d];
  }
  // pad dim 67 = 0
  for (int p = tid; p < FPS_PTS_PER_WG; p += FPS_THREADS)
    ldsx[(33 * FPS_PTS_PER_WG + p) * 2 + 1] = 0.f;

  // q for step 1 = segment point 0
  if (tid < 68) {
    float v = 0.f;
    if (tid < 3)       v = xyz[(size_t)(s * SEG_N) * 3 + tid];
    else if (tid < 67) v = feat[(size_t)(s * SEG_N) * CFEAT + (tid - 3)];
    qbuf[tid] = v;
  }
  if (tid == 0 && wg == 0) fps_idx[s * M_PER_SEG] = 0;
  __syncthreads();

  float D0 = 1e10f, D1 = 1e10f;
  const float4* xp  = (const float4*)ldsx;  // index: dp*256 + tid
  const float2* q2p = (const float2*)qbuf;

  for (int t = 1; t < M_PER_SEG; ++t) {
    // numpy-style pairwise sum: 8 strided accumulators, no fma contraction
    float r0[8] = {0,0,0,0,0,0,0,0};
    float r1[8] = {0,0,0,0,0,0,0,0};
    #pragma unroll
    for (int dp = 0; dp < DPAIRS; ++dp) {
      float4 v = xp[dp * 256 + tid];   // {p0.d0, p0.d1, p1.d0, p1.d1}
      float2 q = q2p[dp];
      float t00 = v.x - q.x, t01 = v.y - q.y;
      float t10 = v.z - q.x, t11 = v.w - q.y;
      float s00 = t00 * t00, s01 = t01 * t01;
      float s10 = t10 * t10, s11 = t11 * t11;
      r0[(2*dp) & 7]     += s00;
      r0[(2*dp + 1) & 7] += s01;
      r1[(2*dp) & 7]     += s10;
      r1[(2*dp + 1) & 7] += s11;
    }
    float a0 = ((r0[0]+r0[1])+(r0[2]+r0[3])) + ((r0[4]+r0[5])+(r0[6]+r0[7]));
    float a1 = ((r1[0]+r1[1])+(r1[2]+r1[3])) + ((r1[4]+r1[5])+(r1[6]+r1[7]));
    D0 = fminf(D0, a0);
    D1 = fminf(D1, a1);

    // per-wave argmax, ties -> lowest index
    float bd; int bi;
    if (D1 > D0) { bd = D1; bi = pbase + 2*tid + 1; }
    else         { bd = D0; bi = pbase + 2*tid;     }
    #pragma unroll
    for (int off = 32; off >= 1; off >>= 1) {
      float od = __shfl_xor(bd, off);
      int   oi = __shfl_xor(bi, off);
      if (od > bd || (od == bd && oi < bi)) { bd = od; bi = oi; }
    }

    u64* base = &cand[(((unsigned)t & 1u) * NSEG + s) * FPS_SLOTS];
    if (lane == 0) {
      u64 pack = ((u64)(unsigned)t << 45)
               | ((u64)__float_as_uint(bd) << 13)
               | (u64)(unsigned)(8191 - bi);
      __hip_atomic_store(&base[wg * 4 + wv], pack,
                         __ATOMIC_RELAXED, __HIP_MEMORY_SCOPE_AGENT);
    }

    if (wv == 0) {
      // poll all 64 slots of my segment (one per lane), RELAXED agent
      u64 v;
      {
        const u64* slot = &base[lane];
        for (;;) {
          v = __hip_atomic_load(slot, __ATOMIC_RELAXED, __HIP_MEMORY_SCOPE_AGENT);
          if ((unsigned)(v >> 45) == (unsigned)t) break;
          __builtin_amdgcn_s_sleep(1);
        }
      }
      // butterfly max over 64 lanes (tag equal; dist then low-idx monotone)
      #pragma unroll
      for (int off = 32; off >= 1; off >>= 1) {
        u64 o = __shfl_xor(v, off);
        if (o > v) v = o;
      }
      int qi = 8191 - (int)(v & 0x1FFFu);
      if (wg == 0 && lane == 0) fps_idx[s * M_PER_SEG + t] = qi;

      // reload q coords from read-only global X (L2-hot: nothing invalidates)
      size_t qb = (size_t)(s * SEG_N + qi);
      float qv;
      if (lane < 3) qv = xyz[qb * 3 + lane];
      else          qv = feat[qb * CFEAT + (lane - 3)];
      qbuf[lane] = qv;
      if (lane < 4) {
        int dd = 64 + lane;
        qbuf[dd] = (dd < 67) ? feat[qb * CFEAT + (dd - 3)] : 0.f;
      }
    }
    __syncthreads();   // single barrier per step
  }
}

// ---------------------------------------------------------------------------
__global__ void gather_kernel(const float* __restrict__ xyz, const float* __restrict__ vel,
                              const int* __restrict__ fps_idx, float* __restrict__ out)
{
  int i = blockIdx.x * 256 + threadIdx.x;
  if (i >= M_TOTAL) return;
  int s = i >> 11, r = i & 2047;
  int g = s * SEG_N + fps_idx[s * M_PER_SEG + r];
  out[OUT_XYZ + i*3 + 0] = xyz[(size_t)g*3 + 0];
  out[OUT_XYZ + i*3 + 1] = xyz[(size_t)g*3 + 1];
  out[OUT_XYZ + i*3 + 2] = xyz[(size_t)g*3 + 2];
  out[OUT_VEL + i*3 + 0] = vel[(size_t)g*3 + 0];
  out[OUT_VEL + i*3 + 1] = vel[(size_t)g*3 + 1];
  out[OUT_VEL + i*3 + 2] = vel[(size_t)g*3 + 2];
  if (i == 0) { out[OUT_OFF] = 2048.0f; out[OUT_OFF + 1] = 4096.0f; }
}

// ---------------------------------------------------------------------------
// kNN: 16 queries/WG, 16 scanner-threads/query. Phase 1: per-thread sorted
// top-16 (med3 chain, values only) over stride-16 candidates from LDS tiles;
// 16-way merge -> exact global 16th-smallest T. Phase 2: rescan, collect
// d2 <= T*(1+eps), pick 16 by (d2, idx).
// ---------------------------------------------------------------------------
#define KNN_TILE 1024
__global__ __launch_bounds__(256)
void knn_kernel(const float* __restrict__ xyz, const float* __restrict__ out,
                int* __restrict__ knn)
{
  __shared__ float px[KNN_TILE], py[KNN_TILE], pz[KNN_TILE];
  __shared__ float ldK[16][16][16];
  __shared__ float Tq[16];
  __shared__ float dbuf[16][24];
  __shared__ int   cbuf[16][24];
  __shared__ int   cnt[16];

  const int tid = threadIdx.x;
  const int ql = tid >> 4, j = tid & 15;
  const int qg = blockIdx.x * 16 + ql;
  const int s  = qg >> 11;
  const float qx = out[OUT_XYZ + qg*3 + 0];
  const float qy = out[OUT_XYZ + qg*3 + 1];
  const float qz = out[OUT_XYZ + qg*3 + 2];
  const float sq = qx*qx + qy*qy + qz*qz;

  float K[16];
  #pragma unroll
  for (int r = 0; r < 16; ++r) K[r] = 3.4e38f;

  for (int tile = 0; tile < SEG_N / KNN_TILE; ++tile) {
    __syncthreads();
    for (int u = tid; u < KNN_TILE; u += 256) {
      size_t g = (size_t)(s * SEG_N + tile * KNN_TILE + u);
      px[u] = xyz[g*3+0]; py[u] = xyz[g*3+1]; pz[u] = xyz[g*3+2];
    }
    __syncthreads();
    #pragma unroll 4
    for (int i = 0; i < KNN_TILE / 16; ++i) {
      int c = i * 16 + j;                       // conflict-free: 16 banks, bcast x4
      float x = px[c], y = py[c], z = pz[c];
      float sp  = x*x + y*y + z*z;
      float dot = qx*x + qy*y + qz*z;
      float d2  = (sq + sp) - 2.0f * dot;
      #pragma unroll
      for (int r = 15; r >= 1; --r)             // branchless sorted insert
        K[r] = fminf(fmaxf(d2, K[r-1]), K[r]);  // med3(d2, K[r-1], K[r])
      K[0] = fminf(K[0], d2);
    }
  }
  #pragma unroll
  for (int r = 0; r < 16; ++r) ldK[ql][j][r] = K[r];
  __syncthreads();

  {
    int head = 0;
    float T = 3.4e38f;
    for (int r = 0; r < 16; ++r) {
      float val = (head < 16) ? ldK[ql][j][head] : 3.4e38f;
      float mv = val; int ml = j;
      #pragma unroll
      for (int off = 8; off >= 1; off >>= 1) {
        float ov = __shfl_xor(mv, off, 16);
        int   ol = __shfl_xor(ml, off, 16);
        if (ov < mv || (ov == mv && ol < ml)) { mv = ov; ml = ol; }
      }
      if (j == ml) head++;
      T = mv;
    }
    if (j == 0) { Tq[ql] = T; cnt[ql] = 0; }
  }
  __syncthreads();
  const float T  = Tq[ql];
  const float Tm = T + fabsf(T) * 1e-6f + 1e-30f;

  for (int tile = 0; tile < SEG_N / KNN_TILE; ++tile) {
    __syncthreads();
    for (int u = tid; u < KNN_TILE; u += 256) {
      size_t g = (size_t)(s * SEG_N + tile * KNN_TILE + u);
      px[u] = xyz[g*3+0]; py[u] = xyz[g*3+1]; pz[u] = xyz[g*3+2];
    }
    __syncthreads();
    for (int i = 0; i < KNN_TILE / 16; ++i) {
      int c = i * 16 + j;
      float x = px[c], y = py[c], z = pz[c];
      float sp  = x*x + y*y + z*z;
      float dot = qx*x + qy*y + qz*z;
      float d2  = (sq + sp) - 2.0f * dot;
      if (d2 <= Tm) {
        int pos = atomicAdd(&cnt[ql], 1);
        if (pos < 24) { dbuf[ql][pos] = d2; cbuf[ql][pos] = tile * KNN_TILE + c; }
      }
    }
  }
  __syncthreads();

  if (j == 0) {
    int n = cnt[ql]; if (n > 24) n = 24;
    for (int r = 0; r < NSAMPLE; ++r) {
      float bv = 3.4e38f; int bc = 0, bp = -1;
      for (int e = 0; e < n; ++e) {
        float dv = dbuf[ql][e]; int cc = cbuf[ql][e];
        if (dv < bv || (dv == bv && cc < bc)) { bv = dv; bc = cc; bp = e; }
      }
      if (bp >= 0) dbuf[ql][bp] = 3.4e38f;
      knn[qg * NSAMPLE + r] = bc;
    }
  }
}

// ---------------------------------------------------------------------------
// Gather 16 neighbor feature rows, Linear(64->128) no bias, ReLU, max over k.
// One WG (128 threads = output channels) per query; W rows live in VGPRs.
// ---------------------------------------------------------------------------
__global__ __launch_bounds__(128)
void gemm_kernel(const float* __restrict__ feat, const float* __restrict__ W,
                 const int* __restrict__ knn, float* __restrict__ out)
{
  __shared__ __align__(16) float f[NSAMPLE][CFEAT];
  __shared__ int kid[NSAMPLE];
  const int tid = threadIdx.x;
  const int q = blockIdx.x;
  const int s = q >> 11;
  if (tid < NSAMPLE) kid[tid] = knn[q * NSAMPLE + tid];
  __syncthreads();
  for (int e = tid; e < NSAMPLE * CFEAT; e += 128) {
    int k = e >> 6, c = e & 63;
    f[k][c] = feat[(size_t)(s * SEG_N + kid[k]) * CFEAT + c];
  }
  float4 w[16];
  const float4* Wrow = (const float4*)(W + (size_t)tid * CFEAT);
  #pragma unroll
  for (int c4 = 0; c4 < 16; ++c4) w[c4] = Wrow[c4];
  __syncthreads();

  float m = -3.4e38f;
  #pragma unroll
  for (int k = 0; k < NSAMPLE; ++k) {
    float acc = 0.f;
    const float4* frow = (const float4*)&f[k][0];
    #pragma unroll
    for (int c4 = 0; c4 < 16; ++c4) {
      float4 fv = frow[c4];
      acc += fv.x * w[c4].x + fv.y * w[c4].y + fv.z * w[c4].z + fv.w * w[c4].w;
    }
    m = fmaxf(m, acc);
  }
  out[OUT_FEAT + (size_t)q * COUT + tid] = fmaxf(m, 0.f);
}

// ---------------------------------------------------------------------------
extern "C" void kernel_launch(void* const* d_in, const int* in_sizes, int n_in,
                              void* d_out, int out_size, void* d_ws, size_t ws_size,
                              hipStream_t stream)
{
  const float* xyz  = (const float*)d_in[0];
  const float* feat = (const float*)d_in[1];
  // d_in[2] = offset (segment sizes are fixed by the problem)
  const float* vel  = (const float*)d_in[3];
  const float* W    = (const float*)d_in[4];
  float* out = (float*)d_out;
  char*  ws  = (char*)d_ws;
  u64* cand    = (u64*)(ws + WS_CAND);
  int* fps_idx = (int*)(ws + WS_FPS);
  int* knn     = (int*)(ws + WS_KNN);

  // parity-tagged candidate slots must start clean every launch
  hipMemsetAsync(cand, 0, 2048, stream);

  (void)hipFuncSetAttribute((const void*)fps_kernel,
                            hipFuncAttributeMaxDynamicSharedMemorySize,
                            FPS_LDS_BYTES);
  fps_kernel<<<NSEG * FPS_WGS_PER_SEG, FPS_THREADS, FPS_LDS_BYTES, stream>>>(
      xyz, feat, cand, fps_idx);
  gather_kernel<<<M_TOTAL / 256, 256, 0, stream>>>(xyz, vel, fps_idx, out);
  knn_kernel<<<M_TOTAL / 16, 256, 0, stream>>>(xyz, out, knn);
  gemm_kernel<<<M_TOTAL, 128, 0, stream>>>(feat, W, knn, out);
}